// Round 7
// baseline (363.476 us; speedup 1.0000x reference)
//
#include <hip/hip_runtime.h>
#include <hip/hip_bf16.h>
#include <stdint.h>

// ---------------------------------------------------------------------------
// DuQuant-style fake-quant linear, MI355X (gfx950)
//   out[m,n] = sx*sw*( dot_i8 - zpx*Sw - zpw*Sx + K*zpx*zpw ) + bias
// fq: one-pass swapped-operand 6-term bf16-split MFMA rotation (r6, proven).
// GEMM v3: 128x128-tile i8 m97-structure, BK=64B, 4 blocks/CU, st_16x32
// swizzled LDS (stage-side inverse + read-side XOR), factored dequant epi.
// ---------------------------------------------------------------------------

typedef __bf16    bf16x8 __attribute__((ext_vector_type(8)));
typedef float     f32x4  __attribute__((ext_vector_type(4)));
typedef int       i32x4  __attribute__((ext_vector_type(4)));
typedef uint32_t  u32;
typedef uint32_t  u32x4  __attribute__((ext_vector_type(4)));

__device__ __forceinline__ void gload_lds16(const void* g, void* l) {
  __builtin_amdgcn_global_load_lds(
      (__attribute__((address_space(1))) void*)(g),
      (__attribute__((address_space(3))) void*)(l), 16, 0, 0);
}

// ---------------------------------------------------------------------------
// prep_rt: 3-way bf16 split of R in MFMA fragment layout (verified r3-r6).
// ---------------------------------------------------------------------------
__global__ __launch_bounds__(256)
void prep_rt(const float* __restrict__ R, unsigned short* __restrict__ RT3)
{
  const int tid = blockIdx.x * 256 + threadIdx.x;   // 0..16383
  const int q  = tid & 7;
  const int l  = (tid >> 3) & 63;
  const int f  = (tid >> 9) & 7;
  const int ks = tid >> 12;
  const float v = R[(ks * 32 + (l >> 4) * 8 + q) * 128 + f * 16 + (l & 15)];
  __hip_bfloat16 h1 = __float2bfloat16(v);
  const float rem = v - __bfloat162float(h1);
  __hip_bfloat16 h2 = __float2bfloat16(rem);
  const float rem2 = rem - __bfloat162float(h2);
  __hip_bfloat16 h3 = __float2bfloat16(rem2);
  RT3[tid]          = *(unsigned short*)&h1;
  RT3[16384 + tid]  = *(unsigned short*)&h2;
  RT3[32768 + tid]  = *(unsigned short*)&h3;
}

// ---------------------------------------------------------------------------
// fq_rot1p: 16 rows/block, 512 threads, ONE pass (unchanged from r6).
// ---------------------------------------------------------------------------
#define FQ_TB  98304
#define FQ_SC  (98304 + 8 * 2560)

__global__ __launch_bounds__(512, 2)
void fq_rot1p(const float* __restrict__ X,
              const unsigned short* __restrict__ RT3,
              uint8_t* __restrict__ Q,
              float4* __restrict__ stats)
{
  __shared__ __align__(16) char lds[98304 + 8 * 2560 + 1664];

  const int t = threadIdx.x, lane = t & 63, wid = t >> 6;
  const size_t rowbase = (size_t)blockIdx.x * 16;
  const int colw = wid * 512;

#pragma unroll
  for (int i = 0; i < 12; ++i)
    gload_lds16((const char*)RT3 + i * 8192 + t * 16, lds + i * 8192 + t * 16);
  asm volatile("s_waitcnt vmcnt(0)" ::: "memory");
  __syncthreads();

  float* smin  = (float*)(lds + FQ_SC);
  float* smax  = (float*)(lds + FQ_SC + 512);
  float* rowsc = (float*)(lds + FQ_SC + 1024);
  float* rowzp = (float*)(lds + FQ_SC + 1088);
  int*   qsumL = (int*)  (lds + FQ_SC + 1152);

  const float* xbase = X + (rowbase + (lane & 15)) * 4096 + colw + (lane >> 4) * 8;

  f32x4 acc[4][8];
#pragma unroll
  for (int b = 0; b < 4; ++b)
#pragma unroll
    for (int f = 0; f < 8; ++f) acc[b][f] = (f32x4){0.f, 0.f, 0.f, 0.f};

#pragma unroll 1
  for (int kk = 0; kk < 4; ++kk) {
    union { bf16x8 v; unsigned short u[8]; } xh[4], xl[4], x2[4];
#pragma unroll
    for (int b = 0; b < 4; ++b) {
      const f32x4 lo = *(const f32x4*)(xbase + b * 128 + kk * 32);
      const f32x4 hi = *(const f32x4*)(xbase + b * 128 + kk * 32 + 4);
#pragma unroll
      for (int e = 0; e < 8; ++e) {
        const float xv = (e < 4) ? lo[e] : hi[e - 4];
        __hip_bfloat16 h1 = __float2bfloat16(xv);
        const float rm = xv - __bfloat162float(h1);
        __hip_bfloat16 h2 = __float2bfloat16(rm);
        const float rm2 = rm - __bfloat162float(h2);
        __hip_bfloat16 h3 = __float2bfloat16(rm2);
        xh[b].u[e] = *(unsigned short*)&h1;
        xl[b].u[e] = *(unsigned short*)&h2;
        x2[b].u[e] = *(unsigned short*)&h3;
      }
    }
#pragma unroll
    for (int f = 0; f < 8; ++f) {
      const int off = ((kk * 8 + f) * 64 + lane) * 16;
      const bf16x8 bh = *(const bf16x8*)(lds + off);
      const bf16x8 bl = *(const bf16x8*)(lds + 32768 + off);
      const bf16x8 b2 = *(const bf16x8*)(lds + 65536 + off);
#pragma unroll
      for (int b = 0; b < 4; ++b) {
        acc[b][f] = __builtin_amdgcn_mfma_f32_16x16x32_bf16(bh, xh[b].v, acc[b][f], 0, 0, 0);
        acc[b][f] = __builtin_amdgcn_mfma_f32_16x16x32_bf16(bh, xl[b].v, acc[b][f], 0, 0, 0);
        acc[b][f] = __builtin_amdgcn_mfma_f32_16x16x32_bf16(bh, x2[b].v, acc[b][f], 0, 0, 0);
        acc[b][f] = __builtin_amdgcn_mfma_f32_16x16x32_bf16(bl, xh[b].v, acc[b][f], 0, 0, 0);
        acc[b][f] = __builtin_amdgcn_mfma_f32_16x16x32_bf16(bl, xl[b].v, acc[b][f], 0, 0, 0);
        acc[b][f] = __builtin_amdgcn_mfma_f32_16x16x32_bf16(b2, xh[b].v, acc[b][f], 0, 0, 0);
      }
    }
  }

  float mn = 0.f, mx = 0.f;
#pragma unroll
  for (int b = 0; b < 4; ++b)
#pragma unroll
    for (int f = 0; f < 8; ++f)
#pragma unroll
      for (int r = 0; r < 4; ++r) {
        mn = fminf(mn, acc[b][f][r]);
        mx = fmaxf(mx, acc[b][f][r]);
      }
  mn = fminf(mn, __shfl_xor(mn, 16, 64));
  mn = fminf(mn, __shfl_xor(mn, 32, 64));
  mx = fmaxf(mx, __shfl_xor(mx, 16, 64));
  mx = fmaxf(mx, __shfl_xor(mx, 32, 64));
  if (lane < 16) { smin[wid * 16 + lane] = mn; smax[wid * 16 + lane] = mx; }
  __syncthreads();
  if (t < 16) {
    float m = 0.f, M = 0.f;
#pragma unroll
    for (int q = 0; q < 8; ++q) {
      m = fminf(m, smin[q * 16 + t]);
      M = fmaxf(M, smax[q * 16 + t]);
    }
    const float sc = fmaxf((M - m) / 15.0f, 1e-5f);
    rowsc[t] = sc;
    rowzp[t] = rintf(-m / sc);
  }
  __syncthreads();
  const float scale = rowsc[lane & 15];
  const float zp    = rowzp[lane & 15];

  u32* tw = (u32*)(lds + FQ_TB + wid * 2560);
  int qsum = 0;
#pragma unroll
  for (int b = 0; b < 4; ++b) {
#pragma unroll
    for (int f = 0; f < 8; ++f) {
      u32 pk = 0;
#pragma unroll
      for (int r = 0; r < 4; ++r) {
        const float qf = fminf(fmaxf(rintf(acc[b][f][r] / scale) + zp, 0.0f), 15.0f);
        const int qi = (int)qf;
        qsum += qi;
        pk |= (u32)qi << (8 * r);
      }
      tw[(lane & 15) * 40 + f * 4 + (lane >> 4)] = pk;
    }
#pragma unroll
    for (int rr = 0; rr < 2; ++rr) {
      const int row = rr * 8 + (lane >> 3);
      const int ch  = lane & 7;
      const u32x4 v = *(const u32x4*)&tw[row * 40 + ch * 4];
      *(u32x4*)(Q + (rowbase + row) * 4096 + colw + b * 128 + ch * 16) = v;
    }
  }

  qsum += __shfl_xor(qsum, 16, 64);
  qsum += __shfl_xor(qsum, 32, 64);
  if (lane < 16) qsumL[wid * 16 + lane] = qsum;
  __syncthreads();
  if (t < 16) {
    int S = 0;
#pragma unroll
    for (int q = 0; q < 8; ++q) S += qsumL[q * 16 + t];
    stats[rowbase + t] = make_float4(rowsc[t], rowzp[t], (float)S, 0.0f);
  }
}

// ---------------------------------------------------------------------------
// prep_cols: factored per-col dequant constants from W stats.
// ---------------------------------------------------------------------------
__global__ __launch_bounds__(256)
void prep_cols(const float4* __restrict__ Wst, float* __restrict__ colS,
               float* __restrict__ colA, float* __restrict__ colB)
{
  const int n = blockIdx.x * 256 + threadIdx.x;
  const float4 w = Wst[n];
  colS[n] = w.x;
  colA[n] = w.x * w.z - 4096.0f * w.x * w.y;
  colB[n] = w.x * w.y;
}

// ---------------------------------------------------------------------------
// GEMM v3: 128x128-tile i8, BK=64 bytes, NT=64, 4 waves (2x2 of 64x64),
// 16 KiB LDS single-buffer, 2-barrier K-step (m97 structure), st_16x32
// swizzle (inverse-swizzled global source, swizzled ds_read), 4 blocks/CU.
// ---------------------------------------------------------------------------
__global__ __launch_bounds__(256, 4)
void gemm128_i8(const uint8_t* __restrict__ Ap,   // [M][4096] codes
                const uint8_t* __restrict__ Bp,   // [4096][4096] codes
                const float4* __restrict__ Xst,   // [M] {sx, zpx, Sx}
                const float* __restrict__ colS,
                const float* __restrict__ colA,
                const float* __restrict__ colB,
                const float* __restrict__ bias,
                float* __restrict__ C)
{
  __shared__ __align__(16) uint8_t lds[16384];   // A[0,8K) B[8K,16K)
  char* ldsB = (char*)lds;
  const char* ldsc = (const char*)lds;

  const int tid  = threadIdx.x;
  const int lane = tid & 63;
  const int wid  = tid >> 6;
  const int wm   = wid >> 1;      // 0..1
  const int wn   = wid & 1;       // 0..1

  // XCD-aware block swizzle (nwg = 2048, divisible by 8)
  int bid = blockIdx.x;
  int nwg = gridDim.x;
  int swz = ((nwg & 7) == 0) ? ((bid & 7) * (nwg >> 3) + (bid >> 3)) : bid;
  const int bm = (swz >> 5) * 128;      // N/128 = 32 n-blocks
  const int bn = (swz & 31) * 128;

  // staging: linear LDS dest, inverse-swizzled global source.
  // half-tile = 128 rows x 64 B = 8 KB; subtile = 16 rows x 64 B = 1024 B;
  // swizzle: byte ^= ((byte>>9)&1)<<5 within each 1024-B subtile.
  const int t16 = tid * 16;
  int stOff0, stOff1;
  {
    int Lb0 = t16;                  // bytes [0,4096)
    int Lb1 = t16 + 4096;           // bytes [4096,8192)
    int Lp0 = Lb0 ^ (((Lb0 >> 9) & 1) << 5);
    int Lp1 = Lb1 ^ (((Lb1 >> 9) & 1) << 5);
    int r0 = ((Lp0 >> 10) << 4) | ((Lp0 & 1023) >> 6);
    int k0 = Lp0 & 63;
    int r1 = ((Lp1 >> 10) << 4) | ((Lp1 & 1023) >> 6);
    int k1 = Lp1 & 63;
    stOff0 = r0 * 4096 + k0;
    stOff1 = r1 * 4096 + k1;
  }

  // swizzled within-subtile read offset (A-frag: row=lane&15, kchunk=lane>>4)
  int swzr = (lane & 15) * 64 + (lane >> 4) * 16;
  swzr ^= ((swzr & 512) ? 32 : 0);

#define STG(GP, GROW, KT, SLOT) do {                                     \
    const uint8_t* _g = (GP) + ((size_t)(GROW)) * 4096 + (KT);           \
    gload_lds16(_g + stOff0, ldsB + (SLOT) + t16);                       \
    gload_lds16(_g + stOff1, ldsB + (SLOT) + 4096 + t16);                \
  } while (0)

  i32x4 acc[4][4];
#pragma unroll
  for (int i = 0; i < 4; ++i)
#pragma unroll
    for (int j = 0; j < 4; ++j) acc[i][j] = (i32x4){0, 0, 0, 0};

  for (int kt = 0; kt < 4096; kt += 64) {
    __syncthreads();                 // prev iter's ds_reads done (lgkm drained)
    STG(Ap, bm, kt, 0);
    STG(Bp, bn, kt, 8192);
    __syncthreads();                 // drains vmcnt(0): staging complete

    i32x4 fa[4], fb[4];
#pragma unroll
    for (int i = 0; i < 4; ++i)
      fa[i] = *(const i32x4*)(ldsc + (wm * 4 + i) * 1024 + swzr);
#pragma unroll
    for (int j = 0; j < 4; ++j)
      fb[j] = *(const i32x4*)(ldsc + 8192 + (wn * 4 + j) * 1024 + swzr);

#pragma unroll
    for (int i = 0; i < 4; ++i)
#pragma unroll
      for (int j = 0; j < 4; ++j)
        acc[i][j] = __builtin_amdgcn_mfma_i32_16x16x64_i8(fa[i], fb[j], acc[i][j], 0, 0, 0);
  }

  // epilogue: C/D layout col=lane&15, row=(lane>>4)*4+reg; factored dequant
#pragma unroll
  for (int j = 0; j < 4; ++j) {
    const int n = bn + wn * 64 + j * 16 + (lane & 15);
    const float cs = colS[n], ca = colA[n], cb = colB[n], bv = bias[n];
#pragma unroll
    for (int i = 0; i < 4; ++i) {
      const int m0 = bm + wm * 64 + i * 16 + (lane >> 4) * 4;
#pragma unroll
      for (int r = 0; r < 4; ++r) {
        const float4 xst = Xst[m0 + r];
        const float d = (float)acc[i][j][r];
        C[(size_t)(m0 + r) * 4096 + n] =
            xst.x * cs * d - (xst.x * xst.y) * ca - (xst.x * xst.z) * cb + bv;
      }
    }
  }
#undef STG
}

// ---------------------------------------------------------------------------
extern "C" void kernel_launch(void* const* d_in, const int* in_sizes, int n_in,
                              void* d_out, int out_size, void* d_ws, size_t ws_size,
                              hipStream_t stream)
{
  const float* x    = (const float*)d_in[0];  // [4,2048,4096]
  const float* wgt  = (const float*)d_in[1];  // [4096,4096]
  const float* bias = (const float*)d_in[2];  // [4096]
  const float* R    = (const float*)d_in[3];  // [128,128]

  const int K = 4096, N = 4096;
  const int M = in_sizes[0] / K;              // 8192

  uint8_t* Qx = (uint8_t*)d_ws;                          // 32 MB
  uint8_t* Qw = Qx + (size_t)M * K;                      // 16 MB
  float4*  Sx = (float4*)(Qw + (size_t)N * K);           // 128 KB
  float4*  Sw = Sx + M;                                  // 64 KB
  unsigned short* RT3 = (unsigned short*)(Sw + N);       // 96 KB
  float* colS = (float*)((char*)RT3 + 98304);            // 16 KB
  float* colA = colS + N;                                // 16 KB
  float* colB = colA + N;                                // 16 KB

  prep_rt<<<64, 256, 0, stream>>>(R, RT3);
  fq_rot1p<<<M / 16, 512, 0, stream>>>(x,   RT3, Qx, Sx);
  fq_rot1p<<<N / 16, 512, 0, stream>>>(wgt, RT3, Qw, Sw);
  prep_cols<<<N / 256, 256, 0, stream>>>(Sw, colS, colA, colB);

  const int nblk = (M / 128) * (N / 128);     // 2048
  gemm128_i8<<<nblk, 256, 0, stream>>>(Qx, Qw, Sx, colS, colA, colB, bias,
                                       (float*)d_out);
}

// Round 9
// 318.379 us; speedup vs baseline: 1.1416x; 1.1416x over previous
//
#include <hip/hip_runtime.h>
#include <hip/hip_bf16.h>
#include <stdint.h>

// ---------------------------------------------------------------------------
// DuQuant-style fake-quant linear, MI355X (gfx950)
//   out[m,n] = sx*sw*( dot_i8 - zpx*Sw - zpw*Sx + K*zpx*zpw ) + bias
// fq: one-pass swapped-operand 6-term bf16-split MFMA rotation (r6, proven).
// GEMM v5: 256x256 8-phase i8, 5 barriers/tile. r8's 4-barrier version raced:
// staging is distributed across waves and vmcnt is PER-WAVE, so the
// end-of-tile vmcnt MUST be followed by a barrier before any wave issues the
// next tile's ds_reads (cross-wave staging visibility). Slot-restage paths
// (B1 in q0, B0 in q2, A in q3) each remain >=1 barrier after read-drain.
// ---------------------------------------------------------------------------

typedef __bf16    bf16x8 __attribute__((ext_vector_type(8)));
typedef float     f32x4  __attribute__((ext_vector_type(4)));
typedef int       i32x4  __attribute__((ext_vector_type(4)));
typedef uint32_t  u32;
typedef uint32_t  u32x4  __attribute__((ext_vector_type(4)));

__device__ __forceinline__ void gload_lds16(const void* g, void* l) {
  __builtin_amdgcn_global_load_lds(
      (__attribute__((address_space(1))) void*)(g),
      (__attribute__((address_space(3))) void*)(l), 16, 0, 0);
}

// ---------------------------------------------------------------------------
// prep_rt: 3-way bf16 split of R in MFMA fragment layout (verified r3-r7).
// ---------------------------------------------------------------------------
__global__ __launch_bounds__(256)
void prep_rt(const float* __restrict__ R, unsigned short* __restrict__ RT3)
{
  const int tid = blockIdx.x * 256 + threadIdx.x;   // 0..16383
  const int q  = tid & 7;
  const int l  = (tid >> 3) & 63;
  const int f  = (tid >> 9) & 7;
  const int ks = tid >> 12;
  const float v = R[(ks * 32 + (l >> 4) * 8 + q) * 128 + f * 16 + (l & 15)];
  __hip_bfloat16 h1 = __float2bfloat16(v);
  const float rem = v - __bfloat162float(h1);
  __hip_bfloat16 h2 = __float2bfloat16(rem);
  const float rem2 = rem - __bfloat162float(h2);
  __hip_bfloat16 h3 = __float2bfloat16(rem2);
  RT3[tid]          = *(unsigned short*)&h1;
  RT3[16384 + tid]  = *(unsigned short*)&h2;
  RT3[32768 + tid]  = *(unsigned short*)&h3;
}

// ---------------------------------------------------------------------------
// fq_rot1p: 16 rows/block, 512 threads, ONE pass (unchanged from r6).
// ---------------------------------------------------------------------------
#define FQ_TB  98304
#define FQ_SC  (98304 + 8 * 2560)

__global__ __launch_bounds__(512, 2)
void fq_rot1p(const float* __restrict__ X,
              const unsigned short* __restrict__ RT3,
              uint8_t* __restrict__ Q,
              float4* __restrict__ stats)
{
  __shared__ __align__(16) char lds[98304 + 8 * 2560 + 1664];

  const int t = threadIdx.x, lane = t & 63, wid = t >> 6;
  const size_t rowbase = (size_t)blockIdx.x * 16;
  const int colw = wid * 512;

#pragma unroll
  for (int i = 0; i < 12; ++i)
    gload_lds16((const char*)RT3 + i * 8192 + t * 16, lds + i * 8192 + t * 16);
  asm volatile("s_waitcnt vmcnt(0)" ::: "memory");
  __syncthreads();

  float* smin  = (float*)(lds + FQ_SC);
  float* smax  = (float*)(lds + FQ_SC + 512);
  float* rowsc = (float*)(lds + FQ_SC + 1024);
  float* rowzp = (float*)(lds + FQ_SC + 1088);
  int*   qsumL = (int*)  (lds + FQ_SC + 1152);

  const float* xbase = X + (rowbase + (lane & 15)) * 4096 + colw + (lane >> 4) * 8;

  f32x4 acc[4][8];
#pragma unroll
  for (int b = 0; b < 4; ++b)
#pragma unroll
    for (int f = 0; f < 8; ++f) acc[b][f] = (f32x4){0.f, 0.f, 0.f, 0.f};

#pragma unroll 1
  for (int kk = 0; kk < 4; ++kk) {
    union { bf16x8 v; unsigned short u[8]; } xh[4], xl[4], x2[4];
#pragma unroll
    for (int b = 0; b < 4; ++b) {
      const f32x4 lo = *(const f32x4*)(xbase + b * 128 + kk * 32);
      const f32x4 hi = *(const f32x4*)(xbase + b * 128 + kk * 32 + 4);
#pragma unroll
      for (int e = 0; e < 8; ++e) {
        const float xv = (e < 4) ? lo[e] : hi[e - 4];
        __hip_bfloat16 h1 = __float2bfloat16(xv);
        const float rm = xv - __bfloat162float(h1);
        __hip_bfloat16 h2 = __float2bfloat16(rm);
        const float rm2 = rm - __bfloat162float(h2);
        __hip_bfloat16 h3 = __float2bfloat16(rm2);
        xh[b].u[e] = *(unsigned short*)&h1;
        xl[b].u[e] = *(unsigned short*)&h2;
        x2[b].u[e] = *(unsigned short*)&h3;
      }
    }
#pragma unroll
    for (int f = 0; f < 8; ++f) {
      const int off = ((kk * 8 + f) * 64 + lane) * 16;
      const bf16x8 bh = *(const bf16x8*)(lds + off);
      const bf16x8 bl = *(const bf16x8*)(lds + 32768 + off);
      const bf16x8 b2 = *(const bf16x8*)(lds + 65536 + off);
#pragma unroll
      for (int b = 0; b < 4; ++b) {
        acc[b][f] = __builtin_amdgcn_mfma_f32_16x16x32_bf16(bh, xh[b].v, acc[b][f], 0, 0, 0);
        acc[b][f] = __builtin_amdgcn_mfma_f32_16x16x32_bf16(bh, xl[b].v, acc[b][f], 0, 0, 0);
        acc[b][f] = __builtin_amdgcn_mfma_f32_16x16x32_bf16(bh, x2[b].v, acc[b][f], 0, 0, 0);
        acc[b][f] = __builtin_amdgcn_mfma_f32_16x16x32_bf16(bl, xh[b].v, acc[b][f], 0, 0, 0);
        acc[b][f] = __builtin_amdgcn_mfma_f32_16x16x32_bf16(bl, xl[b].v, acc[b][f], 0, 0, 0);
        acc[b][f] = __builtin_amdgcn_mfma_f32_16x16x32_bf16(b2, xh[b].v, acc[b][f], 0, 0, 0);
      }
    }
  }

  float mn = 0.f, mx = 0.f;
#pragma unroll
  for (int b = 0; b < 4; ++b)
#pragma unroll
    for (int f = 0; f < 8; ++f)
#pragma unroll
      for (int r = 0; r < 4; ++r) {
        mn = fminf(mn, acc[b][f][r]);
        mx = fmaxf(mx, acc[b][f][r]);
      }
  mn = fminf(mn, __shfl_xor(mn, 16, 64));
  mn = fminf(mn, __shfl_xor(mn, 32, 64));
  mx = fmaxf(mx, __shfl_xor(mx, 16, 64));
  mx = fmaxf(mx, __shfl_xor(mx, 32, 64));
  if (lane < 16) { smin[wid * 16 + lane] = mn; smax[wid * 16 + lane] = mx; }
  __syncthreads();
  if (t < 16) {
    float m = 0.f, M = 0.f;
#pragma unroll
    for (int q = 0; q < 8; ++q) {
      m = fminf(m, smin[q * 16 + t]);
      M = fmaxf(M, smax[q * 16 + t]);
    }
    const float sc = fmaxf((M - m) / 15.0f, 1e-5f);
    rowsc[t] = sc;
    rowzp[t] = rintf(-m / sc);
  }
  __syncthreads();
  const float scale = rowsc[lane & 15];
  const float zp    = rowzp[lane & 15];

  u32* tw = (u32*)(lds + FQ_TB + wid * 2560);
  int qsum = 0;
#pragma unroll
  for (int b = 0; b < 4; ++b) {
#pragma unroll
    for (int f = 0; f < 8; ++f) {
      u32 pk = 0;
#pragma unroll
      for (int r = 0; r < 4; ++r) {
        const float qf = fminf(fmaxf(rintf(acc[b][f][r] / scale) + zp, 0.0f), 15.0f);
        const int qi = (int)qf;
        qsum += qi;
        pk |= (u32)qi << (8 * r);
      }
      tw[(lane & 15) * 40 + f * 4 + (lane >> 4)] = pk;
    }
#pragma unroll
    for (int rr = 0; rr < 2; ++rr) {
      const int row = rr * 8 + (lane >> 3);
      const int ch  = lane & 7;
      const u32x4 v = *(const u32x4*)&tw[row * 40 + ch * 4];
      *(u32x4*)(Q + (rowbase + row) * 4096 + colw + b * 128 + ch * 16) = v;
    }
  }

  qsum += __shfl_xor(qsum, 16, 64);
  qsum += __shfl_xor(qsum, 32, 64);
  if (lane < 16) qsumL[wid * 16 + lane] = qsum;
  __syncthreads();
  if (t < 16) {
    int S = 0;
#pragma unroll
    for (int q = 0; q < 8; ++q) S += qsumL[q * 16 + t];
    stats[rowbase + t] = make_float4(rowsc[t], rowzp[t], (float)S, 0.0f);
  }
}

// ---------------------------------------------------------------------------
// prep_cols: factored per-col dequant constants from W stats.
// ---------------------------------------------------------------------------
__global__ __launch_bounds__(256)
void prep_cols(const float4* __restrict__ Wst, float* __restrict__ colS,
               float* __restrict__ colA, float* __restrict__ colB)
{
  const int n = blockIdx.x * 256 + threadIdx.x;
  const float4 w = Wst[n];
  colS[n] = w.x;
  colA[n] = w.x * w.z - 4096.0f * w.x * w.y;
  colB[n] = w.x * w.y;
}

// ---------------------------------------------------------------------------
// GEMM v5: 256x256 8-phase i8, 5 barriers/tile (4 phase + 1 boundary).
// ---------------------------------------------------------------------------
#define NT 32   // K bytes / 128

__global__ __launch_bounds__(512, 2)
void gemm256_8ph_i8(const uint8_t* __restrict__ Ap,
                    const uint8_t* __restrict__ Bp,
                    const float4* __restrict__ Xst,
                    const float* __restrict__ colS,
                    const float* __restrict__ colA,
                    const float* __restrict__ colB,
                    const float* __restrict__ bias,
                    float* __restrict__ C)
{
  __shared__ __align__(16) uint8_t lds[131072];
  char* ldsB = (char*)lds;
  const char* ldsc = (const char*)lds;

  const int tid  = threadIdx.x;
  const int lane = tid & 63;
  const int wid  = tid >> 6;
  const int wm   = wid >> 2;
  const int wn   = wid & 3;

  int bid = blockIdx.x;
  int nwg = gridDim.x;
  int swz = ((nwg & 7) == 0) ? ((bid & 7) * (nwg >> 3) + (bid >> 3)) : bid;
  const int bm = (swz >> 4) * 256;
  const int bn = (swz & 15) * 256;

  const int t16 = tid * 16;
  int stOff0, stOff1;
  {
    int Lb0 = t16;
    int Lb1 = t16 + 8192;
    int Lp0 = Lb0 ^ (((Lb0 >> 9) & 1) << 5);
    int Lp1 = Lb1 ^ (((Lb1 >> 9) & 1) << 5);
    int s0 = Lp0 >> 10, w0 = Lp0 & 1023;
    int s1 = Lp1 >> 10, w1 = Lp1 & 1023;
    int r0 = ((s0 >> 1) << 4) | (w0 >> 6);
    int k0 = ((s0 & 1) << 6) | (w0 & 63);
    int r1 = ((s1 >> 1) << 4) | (w1 >> 6);
    int k1 = ((s1 & 1) << 6) | (w1 & 63);
    stOff0 = r0 * 4096 + k0;
    stOff1 = r1 * 4096 + k1;
  }

  int swzw = (lane & 15) * 64 + (lane >> 4) * 16;
  swzw ^= ((swzw & 512) ? 32 : 0);

#define STAGE(GP, GROW, KT, SLOT) do {                                   \
    const uint8_t* _g = (GP) + ((size_t)(GROW)) * 4096 + (KT);           \
    gload_lds16(_g + stOff0, ldsB + (SLOT) + t16);                       \
    gload_lds16(_g + stOff1, ldsB + (SLOT) + 8192 + t16);                \
  } while (0)

  i32x4 acc[8][4];
#pragma unroll
  for (int i = 0; i < 8; ++i)
#pragma unroll
    for (int j = 0; j < 4; ++j) acc[i][j] = (i32x4){0, 0, 0, 0};

  // prologue: tile0 {B0,A0,A1,B1} + tile1 {B0,A0,A1}; vmcnt(6) drains tile0
  STAGE(Bp, bn,       0, 32768);
  STAGE(Ap, bm,       0, 0);
  STAGE(Ap, bm + 128, 0, 16384);
  STAGE(Bp, bn + 128, 0, 49152);
  STAGE(Bp, bn,       128, 65536 + 32768);
  STAGE(Ap, bm,       128, 65536);
  STAGE(Ap, bm + 128, 128, 65536 + 16384);
  asm volatile("s_waitcnt vmcnt(6)" ::: "memory");
  __builtin_amdgcn_s_barrier();

  const int wmOff = wm * 16384;
  const int wnOff = (wn >> 1) * 16384 + (wn & 1) * 8192;

#define LDA(P, I, KK) (*(const i32x4*)((P) + ((I) * 2 + (KK)) * 1024))
#define LDB(P, J, KK) (*(const i32x4*)((P) + ((J) * 2 + (KK)) * 1024))

#define MF8(I, AK0, AK1)                                                      \
  acc[I][0] = __builtin_amdgcn_mfma_i32_16x16x64_i8(AK0, b00, acc[I][0], 0, 0, 0); \
  acc[I][1] = __builtin_amdgcn_mfma_i32_16x16x64_i8(AK0, b10, acc[I][1], 0, 0, 0); \
  acc[I][2] = __builtin_amdgcn_mfma_i32_16x16x64_i8(AK0, b20, acc[I][2], 0, 0, 0); \
  acc[I][3] = __builtin_amdgcn_mfma_i32_16x16x64_i8(AK0, b30, acc[I][3], 0, 0, 0); \
  acc[I][0] = __builtin_amdgcn_mfma_i32_16x16x64_i8(AK1, b01, acc[I][0], 0, 0, 0); \
  acc[I][1] = __builtin_amdgcn_mfma_i32_16x16x64_i8(AK1, b11, acc[I][1], 0, 0, 0); \
  acc[I][2] = __builtin_amdgcn_mfma_i32_16x16x64_i8(AK1, b21, acc[I][2], 0, 0, 0); \
  acc[I][3] = __builtin_amdgcn_mfma_i32_16x16x64_i8(AK1, b31, acc[I][3], 0, 0, 0);

#define TILE(T, D) do {                                                       \
    const char* aP = ldsc + (D) * 65536 + wmOff + swzw;                       \
    const char* bP = ldsc + (D) * 65536 + 32768 + wnOff + swzw;               \
    /* ---- q0: read B(8)+A m0,m1(4); stage (T+1).B1 -> D^1 ---- */           \
    i32x4 b00 = LDB(bP, 0, 0), b01 = LDB(bP, 0, 1);                           \
    i32x4 b10 = LDB(bP, 1, 0), b11 = LDB(bP, 1, 1);                           \
    i32x4 b20 = LDB(bP, 2, 0), b21 = LDB(bP, 2, 1);                           \
    i32x4 b30 = LDB(bP, 3, 0), b31 = LDB(bP, 3, 1);                           \
    i32x4 a00 = LDA(aP, 0, 0), a01 = LDA(aP, 0, 1);                           \
    i32x4 a10 = LDA(aP, 1, 0), a11 = LDA(aP, 1, 1);                           \
    if ((T) + 1 < NT) STAGE(Bp, bn + 128, ((T) + 1) * 128, ((D) ^ 1) * 65536 + 49152); \
    __builtin_amdgcn_s_barrier();                                             \
    asm volatile("s_waitcnt lgkmcnt(0)" ::: "memory");                        \
    __builtin_amdgcn_s_setprio(1);                                            \
    MF8(0, a00, a01); MF8(1, a10, a11);                                       \
    __builtin_amdgcn_s_setprio(0);                                            \
    __builtin_amdgcn_sched_barrier(0);                                        \
    /* ---- q1: read A m2..m7 (12) ---- */                                    \
    i32x4 a20 = LDA(aP, 2, 0), a21 = LDA(aP, 2, 1);                           \
    i32x4 a30 = LDA(aP, 3, 0), a31 = LDA(aP, 3, 1);                           \
    i32x4 a40 = LDA(aP, 4, 0), a41 = LDA(aP, 4, 1);                           \
    i32x4 a50 = LDA(aP, 5, 0), a51 = LDA(aP, 5, 1);                           \
    i32x4 a60 = LDA(aP, 6, 0), a61 = LDA(aP, 6, 1);                           \
    i32x4 a70 = LDA(aP, 7, 0), a71 = LDA(aP, 7, 1);                           \
    __builtin_amdgcn_s_barrier();                                             \
    asm volatile("s_waitcnt lgkmcnt(0)" ::: "memory");                        \
    __builtin_amdgcn_s_setprio(1);                                            \
    MF8(2, a20, a21); MF8(3, a30, a31);                                       \
    __builtin_amdgcn_s_setprio(0);                                            \
    __builtin_amdgcn_sched_barrier(0);                                        \
    /* ---- q2: stage (T+2).B0 -> D ---- */                                   \
    if ((T) + 2 < NT) STAGE(Bp, bn, ((T) + 2) * 128, (D) * 65536 + 32768);    \
    __builtin_amdgcn_s_barrier();                                             \
    __builtin_amdgcn_s_setprio(1);                                            \
    MF8(4, a40, a41); MF8(5, a50, a51);                                       \
    __builtin_amdgcn_s_setprio(0);                                            \
    __builtin_amdgcn_sched_barrier(0);                                        \
    /* ---- q3: stage (T+2).A0,A1 -> D ---- */                                \
    if ((T) + 2 < NT) {                                                       \
      STAGE(Ap, bm,       ((T) + 2) * 128, (D) * 65536);                      \
      STAGE(Ap, bm + 128, ((T) + 2) * 128, (D) * 65536 + 16384);              \
    }                                                                         \
    __builtin_amdgcn_s_barrier();                                             \
    __builtin_amdgcn_s_setprio(1);                                            \
    MF8(6, a60, a61); MF8(7, a70, a71);                                       \
    __builtin_amdgcn_s_setprio(0);                                            \
    if ((T) + 2 < NT)      { asm volatile("s_waitcnt vmcnt(6)" ::: "memory"); } \
    else if ((T) + 1 < NT) { asm volatile("s_waitcnt vmcnt(0)" ::: "memory"); } \
    __builtin_amdgcn_sched_barrier(0);                                        \
    /* boundary barrier: vmcnt is per-wave; next tile's ds_reads must not */  \
    /* sample LDS before ALL waves' staged portions have landed (r8 race) */  \
    __builtin_amdgcn_s_barrier();                                             \
  } while (0)

  for (int t = 0; t < NT; t += 2) {
    TILE(t, 0);
    TILE(t + 1, 1);
  }

  // epilogue: transpose through LDS, coalesced full-line stores (r4-proven)
  {
    float* tile = (float*)ldsB;       // [64][268] fp32
    const int P = 268;
#pragma unroll 1
    for (int quarter = 0; quarter < 4; ++quarter) {
      __builtin_amdgcn_s_barrier();
      if (wm == (quarter >> 1)) {
        const int qi0 = (quarter & 1) * 4;
#pragma unroll
        for (int i = 0; i < 4; ++i)
#pragma unroll
          for (int j = 0; j < 4; ++j) {
            const int rl = i * 16 + (lane >> 4) * 4;
            const int cl = wn * 64 + j * 16 + (lane & 15);
#pragma unroll
            for (int r = 0; r < 4; ++r)
              tile[(rl + r) * P + cl] = (float)acc[qi0 + i][j][r];
          }
      }
      __builtin_amdgcn_s_barrier();
#pragma unroll 1
      for (int rr = 0; rr < 8; ++rr) {
        const int rl = wid * 8 + rr;
        const int grow = bm + quarter * 64 + rl;
        const float4 xs4 = Xst[grow];
        const float r1 = xs4.x, r2 = xs4.x * xs4.y, r3 = xs4.x * xs4.z;
        const int n0 = bn + lane * 4;
        const float4 v  = *(const float4*)&tile[rl * P + lane * 4];
        const float4 cs = *(const float4*)&colS[n0];
        const float4 ca = *(const float4*)&colA[n0];
        const float4 cb = *(const float4*)&colB[n0];
        const float4 bi = *(const float4*)&bias[n0];
        float4 o;
        o.x = r1 * cs.x * v.x - r2 * ca.x - r3 * cb.x + bi.x;
        o.y = r1 * cs.y * v.y - r2 * ca.y - r3 * cb.y + bi.y;
        o.z = r1 * cs.z * v.z - r2 * ca.z - r3 * cb.z + bi.z;
        o.w = r1 * cs.w * v.w - r2 * ca.w - r3 * cb.w + bi.w;
        *(float4*)&C[(size_t)grow * 4096 + n0] = o;
      }
    }
  }
#undef TILE
#undef MF8
#undef LDA
#undef LDB
#undef STAGE
}

// ---------------------------------------------------------------------------
extern "C" void kernel_launch(void* const* d_in, const int* in_sizes, int n_in,
                              void* d_out, int out_size, void* d_ws, size_t ws_size,
                              hipStream_t stream)
{
  const float* x    = (const float*)d_in[0];  // [4,2048,4096]
  const float* wgt  = (const float*)d_in[1];  // [4096,4096]
  const float* bias = (const float*)d_in[2];  // [4096]
  const float* R    = (const float*)d_in[3];  // [128,128]

  const int K = 4096, N = 4096;
  const int M = in_sizes[0] / K;              // 8192

  uint8_t* Qx = (uint8_t*)d_ws;                          // 32 MB
  uint8_t* Qw = Qx + (size_t)M * K;                      // 16 MB
  float4*  Sx = (float4*)(Qw + (size_t)N * K);           // 128 KB
  float4*  Sw = Sx + M;                                  // 64 KB
  unsigned short* RT3 = (unsigned short*)(Sw + N);       // 96 KB
  float* colS = (float*)((char*)RT3 + 98304);            // 16 KB
  float* colA = colS + N;                                // 16 KB
  float* colB = colA + N;                                // 16 KB

  prep_rt<<<64, 256, 0, stream>>>(R, RT3);
  fq_rot1p<<<M / 16, 512, 0, stream>>>(x,   RT3, Qx, Sx);
  fq_rot1p<<<N / 16, 512, 0, stream>>>(wgt, RT3, Qw, Sw);
  prep_cols<<<N / 256, 256, 0, stream>>>(Sw, colS, colA, colB);

  const int nblk = (M / 256) * (N / 256);     // 512
  gemm256_8ph_i8<<<nblk, 512, 0, stream>>>(Qx, Qw, Sx, colS, colA, colB, bias,
                                           (float*)d_out);
}

// Round 10
// 317.157 us; speedup vs baseline: 1.1460x; 1.0039x over previous
//
#include <hip/hip_runtime.h>
#include <hip/hip_bf16.h>
#include <stdint.h>

// ---------------------------------------------------------------------------
// DuQuant-style fake-quant linear, MI355X (gfx950)
//   out[m,n] = sx*sw*( dot_i8 - zpx*Sw - zpw*Sx + K*zpx*zpw ) + bias
// fq: one-pass swapped-operand 6-term bf16-split MFMA rotation (r6, proven).
// GEMM v6: 256x256 i8, TWO compute phases/tile (32 MFMA each), 3 barriers.
// Restage invariant (r8 lesson): every slot restage is >=1 full barrier after
// the phase whose lgkmcnt(0) drained that slot's last reads.
//   T.p0 stages (T+1).{B1,A0,A1}->D^1  [read T-1.p0/p1, drained, bnd.bar after]
//   T.p1 stages (T+2).B0->D AFTER p1.bar [read T.p0, drained, p1.bar after]
// Ledger: 6 loads in p0 + 2 in p1; end-of-tile vmcnt(2) completes T+1's 8.
// ---------------------------------------------------------------------------

typedef __bf16    bf16x8 __attribute__((ext_vector_type(8)));
typedef float     f32x4  __attribute__((ext_vector_type(4)));
typedef int       i32x4  __attribute__((ext_vector_type(4)));
typedef uint32_t  u32;
typedef uint32_t  u32x4  __attribute__((ext_vector_type(4)));

__device__ __forceinline__ void gload_lds16(const void* g, void* l) {
  __builtin_amdgcn_global_load_lds(
      (__attribute__((address_space(1))) void*)(g),
      (__attribute__((address_space(3))) void*)(l), 16, 0, 0);
}

// ---------------------------------------------------------------------------
// prep_rt: 3-way bf16 split of R in MFMA fragment layout (verified r3-r9).
// ---------------------------------------------------------------------------
__global__ __launch_bounds__(256)
void prep_rt(const float* __restrict__ R, unsigned short* __restrict__ RT3)
{
  const int tid = blockIdx.x * 256 + threadIdx.x;   // 0..16383
  const int q  = tid & 7;
  const int l  = (tid >> 3) & 63;
  const int f  = (tid >> 9) & 7;
  const int ks = tid >> 12;
  const float v = R[(ks * 32 + (l >> 4) * 8 + q) * 128 + f * 16 + (l & 15)];
  __hip_bfloat16 h1 = __float2bfloat16(v);
  const float rem = v - __bfloat162float(h1);
  __hip_bfloat16 h2 = __float2bfloat16(rem);
  const float rem2 = rem - __bfloat162float(h2);
  __hip_bfloat16 h3 = __float2bfloat16(rem2);
  RT3[tid]          = *(unsigned short*)&h1;
  RT3[16384 + tid]  = *(unsigned short*)&h2;
  RT3[32768 + tid]  = *(unsigned short*)&h3;
}

// ---------------------------------------------------------------------------
// fq_rot1p: 16 rows/block, 512 threads, ONE pass (unchanged from r6).
// ---------------------------------------------------------------------------
#define FQ_TB  98304
#define FQ_SC  (98304 + 8 * 2560)

__global__ __launch_bounds__(512, 2)
void fq_rot1p(const float* __restrict__ X,
              const unsigned short* __restrict__ RT3,
              uint8_t* __restrict__ Q,
              float4* __restrict__ stats)
{
  __shared__ __align__(16) char lds[98304 + 8 * 2560 + 1664];

  const int t = threadIdx.x, lane = t & 63, wid = t >> 6;
  const size_t rowbase = (size_t)blockIdx.x * 16;
  const int colw = wid * 512;

#pragma unroll
  for (int i = 0; i < 12; ++i)
    gload_lds16((const char*)RT3 + i * 8192 + t * 16, lds + i * 8192 + t * 16);
  asm volatile("s_waitcnt vmcnt(0)" ::: "memory");
  __syncthreads();

  float* smin  = (float*)(lds + FQ_SC);
  float* smax  = (float*)(lds + FQ_SC + 512);
  float* rowsc = (float*)(lds + FQ_SC + 1024);
  float* rowzp = (float*)(lds + FQ_SC + 1088);
  int*   qsumL = (int*)  (lds + FQ_SC + 1152);

  const float* xbase = X + (rowbase + (lane & 15)) * 4096 + colw + (lane >> 4) * 8;

  f32x4 acc[4][8];
#pragma unroll
  for (int b = 0; b < 4; ++b)
#pragma unroll
    for (int f = 0; f < 8; ++f) acc[b][f] = (f32x4){0.f, 0.f, 0.f, 0.f};

#pragma unroll 1
  for (int kk = 0; kk < 4; ++kk) {
    union { bf16x8 v; unsigned short u[8]; } xh[4], xl[4], x2[4];
#pragma unroll
    for (int b = 0; b < 4; ++b) {
      const f32x4 lo = *(const f32x4*)(xbase + b * 128 + kk * 32);
      const f32x4 hi = *(const f32x4*)(xbase + b * 128 + kk * 32 + 4);
#pragma unroll
      for (int e = 0; e < 8; ++e) {
        const float xv = (e < 4) ? lo[e] : hi[e - 4];
        __hip_bfloat16 h1 = __float2bfloat16(xv);
        const float rm = xv - __bfloat162float(h1);
        __hip_bfloat16 h2 = __float2bfloat16(rm);
        const float rm2 = rm - __bfloat162float(h2);
        __hip_bfloat16 h3 = __float2bfloat16(rm2);
        xh[b].u[e] = *(unsigned short*)&h1;
        xl[b].u[e] = *(unsigned short*)&h2;
        x2[b].u[e] = *(unsigned short*)&h3;
      }
    }
#pragma unroll
    for (int f = 0; f < 8; ++f) {
      const int off = ((kk * 8 + f) * 64 + lane) * 16;
      const bf16x8 bh = *(const bf16x8*)(lds + off);
      const bf16x8 bl = *(const bf16x8*)(lds + 32768 + off);
      const bf16x8 b2 = *(const bf16x8*)(lds + 65536 + off);
#pragma unroll
      for (int b = 0; b < 4; ++b) {
        acc[b][f] = __builtin_amdgcn_mfma_f32_16x16x32_bf16(bh, xh[b].v, acc[b][f], 0, 0, 0);
        acc[b][f] = __builtin_amdgcn_mfma_f32_16x16x32_bf16(bh, xl[b].v, acc[b][f], 0, 0, 0);
        acc[b][f] = __builtin_amdgcn_mfma_f32_16x16x32_bf16(bh, x2[b].v, acc[b][f], 0, 0, 0);
        acc[b][f] = __builtin_amdgcn_mfma_f32_16x16x32_bf16(bl, xh[b].v, acc[b][f], 0, 0, 0);
        acc[b][f] = __builtin_amdgcn_mfma_f32_16x16x32_bf16(bl, xl[b].v, acc[b][f], 0, 0, 0);
        acc[b][f] = __builtin_amdgcn_mfma_f32_16x16x32_bf16(b2, xh[b].v, acc[b][f], 0, 0, 0);
      }
    }
  }

  float mn = 0.f, mx = 0.f;
#pragma unroll
  for (int b = 0; b < 4; ++b)
#pragma unroll
    for (int f = 0; f < 8; ++f)
#pragma unroll
      for (int r = 0; r < 4; ++r) {
        mn = fminf(mn, acc[b][f][r]);
        mx = fmaxf(mx, acc[b][f][r]);
      }
  mn = fminf(mn, __shfl_xor(mn, 16, 64));
  mn = fminf(mn, __shfl_xor(mn, 32, 64));
  mx = fmaxf(mx, __shfl_xor(mx, 16, 64));
  mx = fmaxf(mx, __shfl_xor(mx, 32, 64));
  if (lane < 16) { smin[wid * 16 + lane] = mn; smax[wid * 16 + lane] = mx; }
  __syncthreads();
  if (t < 16) {
    float m = 0.f, M = 0.f;
#pragma unroll
    for (int q = 0; q < 8; ++q) {
      m = fminf(m, smin[q * 16 + t]);
      M = fmaxf(M, smax[q * 16 + t]);
    }
    const float sc = fmaxf((M - m) / 15.0f, 1e-5f);
    rowsc[t] = sc;
    rowzp[t] = rintf(-m / sc);
  }
  __syncthreads();
  const float scale = rowsc[lane & 15];
  const float zp    = rowzp[lane & 15];

  u32* tw = (u32*)(lds + FQ_TB + wid * 2560);
  int qsum = 0;
#pragma unroll
  for (int b = 0; b < 4; ++b) {
#pragma unroll
    for (int f = 0; f < 8; ++f) {
      u32 pk = 0;
#pragma unroll
      for (int r = 0; r < 4; ++r) {
        const float qf = fminf(fmaxf(rintf(acc[b][f][r] / scale) + zp, 0.0f), 15.0f);
        const int qi = (int)qf;
        qsum += qi;
        pk |= (u32)qi << (8 * r);
      }
      tw[(lane & 15) * 40 + f * 4 + (lane >> 4)] = pk;
    }
#pragma unroll
    for (int rr = 0; rr < 2; ++rr) {
      const int row = rr * 8 + (lane >> 3);
      const int ch  = lane & 7;
      const u32x4 v = *(const u32x4*)&tw[row * 40 + ch * 4];
      *(u32x4*)(Q + (rowbase + row) * 4096 + colw + b * 128 + ch * 16) = v;
    }
  }

  qsum += __shfl_xor(qsum, 16, 64);
  qsum += __shfl_xor(qsum, 32, 64);
  if (lane < 16) qsumL[wid * 16 + lane] = qsum;
  __syncthreads();
  if (t < 16) {
    int S = 0;
#pragma unroll
    for (int q = 0; q < 8; ++q) S += qsumL[q * 16 + t];
    stats[rowbase + t] = make_float4(rowsc[t], rowzp[t], (float)S, 0.0f);
  }
}

// ---------------------------------------------------------------------------
// prep_cols: factored per-col dequant constants from W stats.
// ---------------------------------------------------------------------------
__global__ __launch_bounds__(256)
void prep_cols(const float4* __restrict__ Wst, float* __restrict__ colS,
               float* __restrict__ colA, float* __restrict__ colB)
{
  const int n = blockIdx.x * 256 + threadIdx.x;
  const float4 w = Wst[n];
  colS[n] = w.x;
  colA[n] = w.x * w.z - 4096.0f * w.x * w.y;
  colB[n] = w.x * w.y;
}

// ---------------------------------------------------------------------------
// GEMM v6: 256x256 i8, 2 compute phases/tile, 3 barriers/tile.
// ---------------------------------------------------------------------------
#define NT 32   // K bytes / 128

__global__ __launch_bounds__(512, 2)
void gemm256_2ph_i8(const uint8_t* __restrict__ Ap,
                    const uint8_t* __restrict__ Bp,
                    const float4* __restrict__ Xst,
                    const float* __restrict__ colS,
                    const float* __restrict__ colA,
                    const float* __restrict__ colB,
                    const float* __restrict__ bias,
                    float* __restrict__ C)
{
  __shared__ __align__(16) uint8_t lds[131072];
  char* ldsB = (char*)lds;
  const char* ldsc = (const char*)lds;

  const int tid  = threadIdx.x;
  const int lane = tid & 63;
  const int wid  = tid >> 6;
  const int wm   = wid >> 2;
  const int wn   = wid & 3;

  int bid = blockIdx.x;
  int nwg = gridDim.x;
  int swz = ((nwg & 7) == 0) ? ((bid & 7) * (nwg >> 3) + (bid >> 3)) : bid;
  const int bm = (swz >> 4) * 256;
  const int bn = (swz & 15) * 256;

  const int t16 = tid * 16;
  int stOff0, stOff1;
  {
    int Lb0 = t16;
    int Lb1 = t16 + 8192;
    int Lp0 = Lb0 ^ (((Lb0 >> 9) & 1) << 5);
    int Lp1 = Lb1 ^ (((Lb1 >> 9) & 1) << 5);
    int s0 = Lp0 >> 10, w0 = Lp0 & 1023;
    int s1 = Lp1 >> 10, w1 = Lp1 & 1023;
    int r0 = ((s0 >> 1) << 4) | (w0 >> 6);
    int k0 = ((s0 & 1) << 6) | (w0 & 63);
    int r1 = ((s1 >> 1) << 4) | (w1 >> 6);
    int k1 = ((s1 & 1) << 6) | (w1 & 63);
    stOff0 = r0 * 4096 + k0;
    stOff1 = r1 * 4096 + k1;
  }

  int swzw = (lane & 15) * 64 + (lane >> 4) * 16;
  swzw ^= ((swzw & 512) ? 32 : 0);

#define STAGE(GP, GROW, KT, SLOT) do {                                   \
    const uint8_t* _g = (GP) + ((size_t)(GROW)) * 4096 + (KT);           \
    gload_lds16(_g + stOff0, ldsB + (SLOT) + t16);                       \
    gload_lds16(_g + stOff1, ldsB + (SLOT) + 8192 + t16);                \
  } while (0)

  i32x4 acc[8][4];
#pragma unroll
  for (int i = 0; i < 8; ++i)
#pragma unroll
    for (int j = 0; j < 4; ++j) acc[i][j] = (i32x4){0, 0, 0, 0};

  // prologue: T0 {B0,A0,A1,B1} (8 loads) + T1.B0 (2 loads); vmcnt(2) -> T0 done
  STAGE(Bp, bn,       0, 32768);
  STAGE(Ap, bm,       0, 0);
  STAGE(Ap, bm + 128, 0, 16384);
  STAGE(Bp, bn + 128, 0, 49152);
  STAGE(Bp, bn,       128, 65536 + 32768);
  asm volatile("s_waitcnt vmcnt(2)" ::: "memory");
  __builtin_amdgcn_s_barrier();

  const int wmOff = wm * 16384;
  const int wnOff = (wn >> 1) * 16384 + (wn & 1) * 8192;

#define LDA(P, I, KK) (*(const i32x4*)((P) + ((I) * 2 + (KK)) * 1024))
#define LDB(P, J, KK) (*(const i32x4*)((P) + ((J) * 2 + (KK)) * 1024))

#define MF8(I, AK0, AK1)                                                      \
  acc[I][0] = __builtin_amdgcn_mfma_i32_16x16x64_i8(AK0, b00, acc[I][0], 0, 0, 0); \
  acc[I][1] = __builtin_amdgcn_mfma_i32_16x16x64_i8(AK0, b10, acc[I][1], 0, 0, 0); \
  acc[I][2] = __builtin_amdgcn_mfma_i32_16x16x64_i8(AK0, b20, acc[I][2], 0, 0, 0); \
  acc[I][3] = __builtin_amdgcn_mfma_i32_16x16x64_i8(AK0, b30, acc[I][3], 0, 0, 0); \
  acc[I][0] = __builtin_amdgcn_mfma_i32_16x16x64_i8(AK1, b01, acc[I][0], 0, 0, 0); \
  acc[I][1] = __builtin_amdgcn_mfma_i32_16x16x64_i8(AK1, b11, acc[I][1], 0, 0, 0); \
  acc[I][2] = __builtin_amdgcn_mfma_i32_16x16x64_i8(AK1, b21, acc[I][2], 0, 0, 0); \
  acc[I][3] = __builtin_amdgcn_mfma_i32_16x16x64_i8(AK1, b31, acc[I][3], 0, 0, 0);

#define TILE(T, D) do {                                                       \
    const char* aP = ldsc + (D) * 65536 + wmOff + swzw;                       \
    const char* bP = ldsc + (D) * 65536 + 32768 + wnOff + swzw;               \
    /* ---- p0: read B(8) + A m0..m3(8); stage (T+1).{B1,A0,A1} -> D^1 ---- */\
    i32x4 b00 = LDB(bP, 0, 0), b01 = LDB(bP, 0, 1);                           \
    i32x4 b10 = LDB(bP, 1, 0), b11 = LDB(bP, 1, 1);                           \
    i32x4 b20 = LDB(bP, 2, 0), b21 = LDB(bP, 2, 1);                           \
    i32x4 b30 = LDB(bP, 3, 0), b31 = LDB(bP, 3, 1);                           \
    i32x4 a00 = LDA(aP, 0, 0), a01 = LDA(aP, 0, 1);                           \
    i32x4 a10 = LDA(aP, 1, 0), a11 = LDA(aP, 1, 1);                           \
    i32x4 a20 = LDA(aP, 2, 0), a21 = LDA(aP, 2, 1);                           \
    i32x4 a30 = LDA(aP, 3, 0), a31 = LDA(aP, 3, 1);                           \
    if ((T) + 1 < NT) {                                                       \
      STAGE(Bp, bn + 128, ((T) + 1) * 128, ((D) ^ 1) * 65536 + 49152);        \
      STAGE(Ap, bm,       ((T) + 1) * 128, ((D) ^ 1) * 65536);                \
      STAGE(Ap, bm + 128, ((T) + 1) * 128, ((D) ^ 1) * 65536 + 16384);        \
    }                                                                         \
    __builtin_amdgcn_s_barrier();                                             \
    asm volatile("s_waitcnt lgkmcnt(0)" ::: "memory");                        \
    __builtin_amdgcn_s_setprio(1);                                            \
    MF8(0, a00, a01); MF8(1, a10, a11); MF8(2, a20, a21); MF8(3, a30, a31);   \
    __builtin_amdgcn_s_setprio(0);                                            \
    __builtin_amdgcn_sched_barrier(0);                                        \
    /* ---- p1: read A m4..m7(8); stage (T+2).B0 -> D after barrier ---- */   \
    i32x4 a40 = LDA(aP, 4, 0), a41 = LDA(aP, 4, 1);                           \
    i32x4 a50 = LDA(aP, 5, 0), a51 = LDA(aP, 5, 1);                           \
    i32x4 a60 = LDA(aP, 6, 0), a61 = LDA(aP, 6, 1);                           \
    i32x4 a70 = LDA(aP, 7, 0), a71 = LDA(aP, 7, 1);                           \
    __builtin_amdgcn_s_barrier();                                             \
    asm volatile("s_waitcnt lgkmcnt(0)" ::: "memory");                        \
    if ((T) + 2 < NT) STAGE(Bp, bn, ((T) + 2) * 128, (D) * 65536 + 32768);    \
    __builtin_amdgcn_s_setprio(1);                                            \
    MF8(4, a40, a41); MF8(5, a50, a51); MF8(6, a60, a61); MF8(7, a70, a71);   \
    __builtin_amdgcn_s_setprio(0);                                            \
    if ((T) + 2 < NT)      { asm volatile("s_waitcnt vmcnt(2)" ::: "memory"); } \
    else if ((T) + 1 < NT) { asm volatile("s_waitcnt vmcnt(0)" ::: "memory"); } \
    __builtin_amdgcn_sched_barrier(0);                                        \
    /* boundary: publish all waves' staging before next tile's ds_reads */    \
    __builtin_amdgcn_s_barrier();                                             \
  } while (0)

  for (int t = 0; t < NT; t += 2) {
    TILE(t, 0);
    TILE(t + 1, 1);
  }

  // epilogue: transpose through LDS, coalesced full-line stores (r4-proven)
  {
    float* tile = (float*)ldsB;       // [64][268] fp32
    const int P = 268;
#pragma unroll 1
    for (int quarter = 0; quarter < 4; ++quarter) {
      __builtin_amdgcn_s_barrier();
      if (wm == (quarter >> 1)) {
        const int qi0 = (quarter & 1) * 4;
#pragma unroll
        for (int i = 0; i < 4; ++i)
#pragma unroll
          for (int j = 0; j < 4; ++j) {
            const int rl = i * 16 + (lane >> 4) * 4;
            const int cl = wn * 64 + j * 16 + (lane & 15);
#pragma unroll
            for (int r = 0; r < 4; ++r)
              tile[(rl + r) * P + cl] = (float)acc[qi0 + i][j][r];
          }
      }
      __builtin_amdgcn_s_barrier();
#pragma unroll 1
      for (int rr = 0; rr < 8; ++rr) {
        const int rl = wid * 8 + rr;
        const int grow = bm + quarter * 64 + rl;
        const float4 xs4 = Xst[grow];
        const float r1 = xs4.x, r2 = xs4.x * xs4.y, r3 = xs4.x * xs4.z;
        const int n0 = bn + lane * 4;
        const float4 v  = *(const float4*)&tile[rl * P + lane * 4];
        const float4 cs = *(const float4*)&colS[n0];
        const float4 ca = *(const float4*)&colA[n0];
        const float4 cb = *(const float4*)&colB[n0];
        const float4 bi = *(const float4*)&bias[n0];
        float4 o;
        o.x = r1 * cs.x * v.x - r2 * ca.x - r3 * cb.x + bi.x;
        o.y = r1 * cs.y * v.y - r2 * ca.y - r3 * cb.y + bi.y;
        o.z = r1 * cs.z * v.z - r2 * ca.z - r3 * cb.z + bi.z;
        o.w = r1 * cs.w * v.w - r2 * ca.w - r3 * cb.w + bi.w;
        *(float4*)&C[(size_t)grow * 4096 + n0] = o;
      }
    }
  }
#undef TILE
#undef MF8
#undef LDA
#undef LDB
#undef STAGE
}

// ---------------------------------------------------------------------------
extern "C" void kernel_launch(void* const* d_in, const int* in_sizes, int n_in,
                              void* d_out, int out_size, void* d_ws, size_t ws_size,
                              hipStream_t stream)
{
  const float* x    = (const float*)d_in[0];  // [4,2048,4096]
  const float* wgt  = (const float*)d_in[1];  // [4096,4096]
  const float* bias = (const float*)d_in[2];  // [4096]
  const float* R    = (const float*)d_in[3];  // [128,128]

  const int K = 4096, N = 4096;
  const int M = in_sizes[0] / K;              // 8192

  uint8_t* Qx = (uint8_t*)d_ws;                          // 32 MB
  uint8_t* Qw = Qx + (size_t)M * K;                      // 16 MB
  float4*  Sx = (float4*)(Qw + (size_t)N * K);           // 128 KB
  float4*  Sw = Sx + M;                                  // 64 KB
  unsigned short* RT3 = (unsigned short*)(Sw + N);       // 96 KB
  float* colS = (float*)((char*)RT3 + 98304);            // 16 KB
  float* colA = colS + N;                                // 16 KB
  float* colB = colA + N;                                // 16 KB

  prep_rt<<<64, 256, 0, stream>>>(R, RT3);
  fq_rot1p<<<M / 16, 512, 0, stream>>>(x,   RT3, Qx, Sx);
  fq_rot1p<<<N / 16, 512, 0, stream>>>(wgt, RT3, Qw, Sw);
  prep_cols<<<N / 256, 256, 0, stream>>>(Sw, colS, colA, colB);

  const int nblk = (M / 256) * (N / 256);     // 512
  gemm256_2ph_i8<<<nblk, 512, 0, stream>>>(Qx, Qw, Sx, colS, colA, colB, bias,
                                           (float*)d_out);
}

// Round 12
// 286.558 us; speedup vs baseline: 1.2684x; 1.1068x over previous
//
#include <hip/hip_runtime.h>
#include <hip/hip_bf16.h>
#include <stdint.h>

// ---------------------------------------------------------------------------
// DuQuant-style fake-quant linear, MI355X (gfx950)
//   out[m,n] = sx*sw*( dot_i8 - zpx*Sw - zpw*Sx + K*zpx*zpw ) + bias
// fq: one-pass swapped-operand 6-term bf16-split MFMA rotation (r6, proven).
// GEMM v7 = r9 (8-phase, 5-barrier, best 213us) + two isolated probes:
//   (a) nontemporal C stores (via ext_vector f32x4 — HIP float4 rejected)
//   (b) k-outer MFMA ordering -> dependent-pair distance 4 -> 8 (i8 latency)
// ---------------------------------------------------------------------------

typedef __bf16    bf16x8 __attribute__((ext_vector_type(8)));
typedef float     f32x4  __attribute__((ext_vector_type(4)));
typedef int       i32x4  __attribute__((ext_vector_type(4)));
typedef uint32_t  u32;
typedef uint32_t  u32x4  __attribute__((ext_vector_type(4)));

__device__ __forceinline__ void gload_lds16(const void* g, void* l) {
  __builtin_amdgcn_global_load_lds(
      (__attribute__((address_space(1))) void*)(g),
      (__attribute__((address_space(3))) void*)(l), 16, 0, 0);
}

// ---------------------------------------------------------------------------
// prep_rt: 3-way bf16 split of R in MFMA fragment layout (verified r3-r10).
// ---------------------------------------------------------------------------
__global__ __launch_bounds__(256)
void prep_rt(const float* __restrict__ R, unsigned short* __restrict__ RT3)
{
  const int tid = blockIdx.x * 256 + threadIdx.x;   // 0..16383
  const int q  = tid & 7;
  const int l  = (tid >> 3) & 63;
  const int f  = (tid >> 9) & 7;
  const int ks = tid >> 12;
  const float v = R[(ks * 32 + (l >> 4) * 8 + q) * 128 + f * 16 + (l & 15)];
  __hip_bfloat16 h1 = __float2bfloat16(v);
  const float rem = v - __bfloat162float(h1);
  __hip_bfloat16 h2 = __float2bfloat16(rem);
  const float rem2 = rem - __bfloat162float(h2);
  __hip_bfloat16 h3 = __float2bfloat16(rem2);
  RT3[tid]          = *(unsigned short*)&h1;
  RT3[16384 + tid]  = *(unsigned short*)&h2;
  RT3[32768 + tid]  = *(unsigned short*)&h3;
}

// ---------------------------------------------------------------------------
// fq_rot1p: 16 rows/block, 512 threads, ONE pass (unchanged from r6).
// ---------------------------------------------------------------------------
#define FQ_TB  98304
#define FQ_SC  (98304 + 8 * 2560)

__global__ __launch_bounds__(512, 2)
void fq_rot1p(const float* __restrict__ X,
              const unsigned short* __restrict__ RT3,
              uint8_t* __restrict__ Q,
              float4* __restrict__ stats)
{
  __shared__ __align__(16) char lds[98304 + 8 * 2560 + 1664];

  const int t = threadIdx.x, lane = t & 63, wid = t >> 6;
  const size_t rowbase = (size_t)blockIdx.x * 16;
  const int colw = wid * 512;

#pragma unroll
  for (int i = 0; i < 12; ++i)
    gload_lds16((const char*)RT3 + i * 8192 + t * 16, lds + i * 8192 + t * 16);
  asm volatile("s_waitcnt vmcnt(0)" ::: "memory");
  __syncthreads();

  float* smin  = (float*)(lds + FQ_SC);
  float* smax  = (float*)(lds + FQ_SC + 512);
  float* rowsc = (float*)(lds + FQ_SC + 1024);
  float* rowzp = (float*)(lds + FQ_SC + 1088);
  int*   qsumL = (int*)  (lds + FQ_SC + 1152);

  const float* xbase = X + (rowbase + (lane & 15)) * 4096 + colw + (lane >> 4) * 8;

  f32x4 acc[4][8];
#pragma unroll
  for (int b = 0; b < 4; ++b)
#pragma unroll
    for (int f = 0; f < 8; ++f) acc[b][f] = (f32x4){0.f, 0.f, 0.f, 0.f};

#pragma unroll 1
  for (int kk = 0; kk < 4; ++kk) {
    union { bf16x8 v; unsigned short u[8]; } xh[4], xl[4], x2[4];
#pragma unroll
    for (int b = 0; b < 4; ++b) {
      const f32x4 lo = *(const f32x4*)(xbase + b * 128 + kk * 32);
      const f32x4 hi = *(const f32x4*)(xbase + b * 128 + kk * 32 + 4);
#pragma unroll
      for (int e = 0; e < 8; ++e) {
        const float xv = (e < 4) ? lo[e] : hi[e - 4];
        __hip_bfloat16 h1 = __float2bfloat16(xv);
        const float rm = xv - __bfloat162float(h1);
        __hip_bfloat16 h2 = __float2bfloat16(rm);
        const float rm2 = rm - __bfloat162float(h2);
        __hip_bfloat16 h3 = __float2bfloat16(rm2);
        xh[b].u[e] = *(unsigned short*)&h1;
        xl[b].u[e] = *(unsigned short*)&h2;
        x2[b].u[e] = *(unsigned short*)&h3;
      }
    }
#pragma unroll
    for (int f = 0; f < 8; ++f) {
      const int off = ((kk * 8 + f) * 64 + lane) * 16;
      const bf16x8 bh = *(const bf16x8*)(lds + off);
      const bf16x8 bl = *(const bf16x8*)(lds + 32768 + off);
      const bf16x8 b2 = *(const bf16x8*)(lds + 65536 + off);
#pragma unroll
      for (int b = 0; b < 4; ++b) {
        acc[b][f] = __builtin_amdgcn_mfma_f32_16x16x32_bf16(bh, xh[b].v, acc[b][f], 0, 0, 0);
        acc[b][f] = __builtin_amdgcn_mfma_f32_16x16x32_bf16(bh, xl[b].v, acc[b][f], 0, 0, 0);
        acc[b][f] = __builtin_amdgcn_mfma_f32_16x16x32_bf16(bh, x2[b].v, acc[b][f], 0, 0, 0);
        acc[b][f] = __builtin_amdgcn_mfma_f32_16x16x32_bf16(bl, xh[b].v, acc[b][f], 0, 0, 0);
        acc[b][f] = __builtin_amdgcn_mfma_f32_16x16x32_bf16(bl, xl[b].v, acc[b][f], 0, 0, 0);
        acc[b][f] = __builtin_amdgcn_mfma_f32_16x16x32_bf16(b2, xh[b].v, acc[b][f], 0, 0, 0);
      }
    }
  }

  float mn = 0.f, mx = 0.f;
#pragma unroll
  for (int b = 0; b < 4; ++b)
#pragma unroll
    for (int f = 0; f < 8; ++f)
#pragma unroll
      for (int r = 0; r < 4; ++r) {
        mn = fminf(mn, acc[b][f][r]);
        mx = fmaxf(mx, acc[b][f][r]);
      }
  mn = fminf(mn, __shfl_xor(mn, 16, 64));
  mn = fminf(mn, __shfl_xor(mn, 32, 64));
  mx = fmaxf(mx, __shfl_xor(mx, 16, 64));
  mx = fmaxf(mx, __shfl_xor(mx, 32, 64));
  if (lane < 16) { smin[wid * 16 + lane] = mn; smax[wid * 16 + lane] = mx; }
  __syncthreads();
  if (t < 16) {
    float m = 0.f, M = 0.f;
#pragma unroll
    for (int q = 0; q < 8; ++q) {
      m = fminf(m, smin[q * 16 + t]);
      M = fmaxf(M, smax[q * 16 + t]);
    }
    const float sc = fmaxf((M - m) / 15.0f, 1e-5f);
    rowsc[t] = sc;
    rowzp[t] = rintf(-m / sc);
  }
  __syncthreads();
  const float scale = rowsc[lane & 15];
  const float zp    = rowzp[lane & 15];

  u32* tw = (u32*)(lds + FQ_TB + wid * 2560);
  int qsum = 0;
#pragma unroll
  for (int b = 0; b < 4; ++b) {
#pragma unroll
    for (int f = 0; f < 8; ++f) {
      u32 pk = 0;
#pragma unroll
      for (int r = 0; r < 4; ++r) {
        const float qf = fminf(fmaxf(rintf(acc[b][f][r] / scale) + zp, 0.0f), 15.0f);
        const int qi = (int)qf;
        qsum += qi;
        pk |= (u32)qi << (8 * r);
      }
      tw[(lane & 15) * 40 + f * 4 + (lane >> 4)] = pk;
    }
#pragma unroll
    for (int rr = 0; rr < 2; ++rr) {
      const int row = rr * 8 + (lane >> 3);
      const int ch  = lane & 7;
      const u32x4 v = *(const u32x4*)&tw[row * 40 + ch * 4];
      *(u32x4*)(Q + (rowbase + row) * 4096 + colw + b * 128 + ch * 16) = v;
    }
  }

  qsum += __shfl_xor(qsum, 16, 64);
  qsum += __shfl_xor(qsum, 32, 64);
  if (lane < 16) qsumL[wid * 16 + lane] = qsum;
  __syncthreads();
  if (t < 16) {
    int S = 0;
#pragma unroll
    for (int q = 0; q < 8; ++q) S += qsumL[q * 16 + t];
    stats[rowbase + t] = make_float4(rowsc[t], rowzp[t], (float)S, 0.0f);
  }
}

// ---------------------------------------------------------------------------
// prep_cols: factored per-col dequant constants from W stats.
// ---------------------------------------------------------------------------
__global__ __launch_bounds__(256)
void prep_cols(const float4* __restrict__ Wst, float* __restrict__ colS,
               float* __restrict__ colA, float* __restrict__ colB)
{
  const int n = blockIdx.x * 256 + threadIdx.x;
  const float4 w = Wst[n];
  colS[n] = w.x;
  colA[n] = w.x * w.z - 4096.0f * w.x * w.y;
  colB[n] = w.x * w.y;
}

// ---------------------------------------------------------------------------
// GEMM v7: 256x256 8-phase i8, 5 barriers/tile, k-outer MFMA order,
// nontemporal C stores (ext_vector f32x4).
// ---------------------------------------------------------------------------
#define NT 32   // K bytes / 128

__global__ __launch_bounds__(512, 2)
void gemm256_8ph_i8(const uint8_t* __restrict__ Ap,
                    const uint8_t* __restrict__ Bp,
                    const float4* __restrict__ Xst,
                    const float* __restrict__ colS,
                    const float* __restrict__ colA,
                    const float* __restrict__ colB,
                    const float* __restrict__ bias,
                    float* __restrict__ C)
{
  __shared__ __align__(16) uint8_t lds[131072];
  char* ldsB = (char*)lds;
  const char* ldsc = (const char*)lds;

  const int tid  = threadIdx.x;
  const int lane = tid & 63;
  const int wid  = tid >> 6;
  const int wm   = wid >> 2;
  const int wn   = wid & 3;

  int bid = blockIdx.x;
  int nwg = gridDim.x;
  int swz = ((nwg & 7) == 0) ? ((bid & 7) * (nwg >> 3) + (bid >> 3)) : bid;
  const int bm = (swz >> 4) * 256;
  const int bn = (swz & 15) * 256;

  const int t16 = tid * 16;
  int stOff0, stOff1;
  {
    int Lb0 = t16;
    int Lb1 = t16 + 8192;
    int Lp0 = Lb0 ^ (((Lb0 >> 9) & 1) << 5);
    int Lp1 = Lb1 ^ (((Lb1 >> 9) & 1) << 5);
    int s0 = Lp0 >> 10, w0 = Lp0 & 1023;
    int s1 = Lp1 >> 10, w1 = Lp1 & 1023;
    int r0 = ((s0 >> 1) << 4) | (w0 >> 6);
    int k0 = ((s0 & 1) << 6) | (w0 & 63);
    int r1 = ((s1 >> 1) << 4) | (w1 >> 6);
    int k1 = ((s1 & 1) << 6) | (w1 & 63);
    stOff0 = r0 * 4096 + k0;
    stOff1 = r1 * 4096 + k1;
  }

  int swzw = (lane & 15) * 64 + (lane >> 4) * 16;
  swzw ^= ((swzw & 512) ? 32 : 0);

#define STAGE(GP, GROW, KT, SLOT) do {                                   \
    const uint8_t* _g = (GP) + ((size_t)(GROW)) * 4096 + (KT);           \
    gload_lds16(_g + stOff0, ldsB + (SLOT) + t16);                       \
    gload_lds16(_g + stOff1, ldsB + (SLOT) + 8192 + t16);                \
  } while (0)

  i32x4 acc[8][4];
#pragma unroll
  for (int i = 0; i < 8; ++i)
#pragma unroll
    for (int j = 0; j < 4; ++j) acc[i][j] = (i32x4){0, 0, 0, 0};

  // prologue: tile0 {B0,A0,A1,B1} + tile1 {B0,A0,A1}; vmcnt(6) drains tile0
  STAGE(Bp, bn,       0, 32768);
  STAGE(Ap, bm,       0, 0);
  STAGE(Ap, bm + 128, 0, 16384);
  STAGE(Bp, bn + 128, 0, 49152);
  STAGE(Bp, bn,       128, 65536 + 32768);
  STAGE(Ap, bm,       128, 65536);
  STAGE(Ap, bm + 128, 128, 65536 + 16384);
  asm volatile("s_waitcnt vmcnt(6)" ::: "memory");
  __builtin_amdgcn_s_barrier();

  const int wmOff = wm * 16384;
  const int wnOff = (wn >> 1) * 16384 + (wn & 1) * 8192;

#define LDA(P, I, KK) (*(const i32x4*)((P) + ((I) * 2 + (KK)) * 1024))
#define LDB(P, J, KK) (*(const i32x4*)((P) + ((J) * 2 + (KK)) * 1024))

// k-outer ordering: all k0 MFMAs for both rows, then all k1 — dependent-pair
// distance 8 (was 4 in MF8) to cover i8 MFMA latency at 2 waves/SIMD.
#define MF16(I0, A00, A01, I1, A10, A11)                                      \
  acc[I0][0] = __builtin_amdgcn_mfma_i32_16x16x64_i8(A00, b00, acc[I0][0], 0, 0, 0); \
  acc[I0][1] = __builtin_amdgcn_mfma_i32_16x16x64_i8(A00, b10, acc[I0][1], 0, 0, 0); \
  acc[I0][2] = __builtin_amdgcn_mfma_i32_16x16x64_i8(A00, b20, acc[I0][2], 0, 0, 0); \
  acc[I0][3] = __builtin_amdgcn_mfma_i32_16x16x64_i8(A00, b30, acc[I0][3], 0, 0, 0); \
  acc[I1][0] = __builtin_amdgcn_mfma_i32_16x16x64_i8(A10, b00, acc[I1][0], 0, 0, 0); \
  acc[I1][1] = __builtin_amdgcn_mfma_i32_16x16x64_i8(A10, b10, acc[I1][1], 0, 0, 0); \
  acc[I1][2] = __builtin_amdgcn_mfma_i32_16x16x64_i8(A10, b20, acc[I1][2], 0, 0, 0); \
  acc[I1][3] = __builtin_amdgcn_mfma_i32_16x16x64_i8(A10, b30, acc[I1][3], 0, 0, 0); \
  acc[I0][0] = __builtin_amdgcn_mfma_i32_16x16x64_i8(A01, b01, acc[I0][0], 0, 0, 0); \
  acc[I0][1] = __builtin_amdgcn_mfma_i32_16x16x64_i8(A01, b11, acc[I0][1], 0, 0, 0); \
  acc[I0][2] = __builtin_amdgcn_mfma_i32_16x16x64_i8(A01, b21, acc[I0][2], 0, 0, 0); \
  acc[I0][3] = __builtin_amdgcn_mfma_i32_16x16x64_i8(A01, b31, acc[I0][3], 0, 0, 0); \
  acc[I1][0] = __builtin_amdgcn_mfma_i32_16x16x64_i8(A11, b01, acc[I1][0], 0, 0, 0); \
  acc[I1][1] = __builtin_amdgcn_mfma_i32_16x16x64_i8(A11, b11, acc[I1][1], 0, 0, 0); \
  acc[I1][2] = __builtin_amdgcn_mfma_i32_16x16x64_i8(A11, b21, acc[I1][2], 0, 0, 0); \
  acc[I1][3] = __builtin_amdgcn_mfma_i32_16x16x64_i8(A11, b31, acc[I1][3], 0, 0, 0);

#define TILE(T, D) do {                                                       \
    const char* aP = ldsc + (D) * 65536 + wmOff + swzw;                       \
    const char* bP = ldsc + (D) * 65536 + 32768 + wnOff + swzw;               \
    /* ---- q0: read B(8)+A m0,m1(4); stage (T+1).B1 -> D^1 ---- */           \
    i32x4 b00 = LDB(bP, 0, 0), b01 = LDB(bP, 0, 1);                           \
    i32x4 b10 = LDB(bP, 1, 0), b11 = LDB(bP, 1, 1);                           \
    i32x4 b20 = LDB(bP, 2, 0), b21 = LDB(bP, 2, 1);                           \
    i32x4 b30 = LDB(bP, 3, 0), b31 = LDB(bP, 3, 1);                           \
    i32x4 a00 = LDA(aP, 0, 0), a01 = LDA(aP, 0, 1);                           \
    i32x4 a10 = LDA(aP, 1, 0), a11 = LDA(aP, 1, 1);                           \
    if ((T) + 1 < NT) STAGE(Bp, bn + 128, ((T) + 1) * 128, ((D) ^ 1) * 65536 + 49152); \
    __builtin_amdgcn_s_barrier();                                             \
    asm volatile("s_waitcnt lgkmcnt(0)" ::: "memory");                        \
    __builtin_amdgcn_s_setprio(1);                                            \
    MF16(0, a00, a01, 1, a10, a11);                                           \
    __builtin_amdgcn_s_setprio(0);                                            \
    __builtin_amdgcn_sched_barrier(0);                                        \
    /* ---- q1: read A m2..m7 (12) ---- */                                    \
    i32x4 a20 = LDA(aP, 2, 0), a21 = LDA(aP, 2, 1);                           \
    i32x4 a30 = LDA(aP, 3, 0), a31 = LDA(aP, 3, 1);                           \
    i32x4 a40 = LDA(aP, 4, 0), a41 = LDA(aP, 4, 1);                           \
    i32x4 a50 = LDA(aP, 5, 0), a51 = LDA(aP, 5, 1);                           \
    i32x4 a60 = LDA(aP, 6, 0), a61 = LDA(aP, 6, 1);                           \
    i32x4 a70 = LDA(aP, 7, 0), a71 = LDA(aP, 7, 1);                           \
    __builtin_amdgcn_s_barrier();                                             \
    asm volatile("s_waitcnt lgkmcnt(0)" ::: "memory");                        \
    __builtin_amdgcn_s_setprio(1);                                            \
    MF16(2, a20, a21, 3, a30, a31);                                           \
    __builtin_amdgcn_s_setprio(0);                                            \
    __builtin_amdgcn_sched_barrier(0);                                        \
    /* ---- q2: stage (T+2).B0 -> D ---- */                                   \
    if ((T) + 2 < NT) STAGE(Bp, bn, ((T) + 2) * 128, (D) * 65536 + 32768);    \
    __builtin_amdgcn_s_barrier();                                             \
    __builtin_amdgcn_s_setprio(1);                                            \
    MF16(4, a40, a41, 5, a50, a51);                                           \
    __builtin_amdgcn_s_setprio(0);                                            \
    __builtin_amdgcn_sched_barrier(0);                                        \
    /* ---- q3: stage (T+2).A0,A1 -> D ---- */                                \
    if ((T) + 2 < NT) {                                                       \
      STAGE(Ap, bm,       ((T) + 2) * 128, (D) * 65536);                      \
      STAGE(Ap, bm + 128, ((T) + 2) * 128, (D) * 65536 + 16384);              \
    }                                                                         \
    __builtin_amdgcn_s_barrier();                                             \
    __builtin_amdgcn_s_setprio(1);                                            \
    MF16(6, a60, a61, 7, a70, a71);                                           \
    __builtin_amdgcn_s_setprio(0);                                            \
    if ((T) + 2 < NT)      { asm volatile("s_waitcnt vmcnt(6)" ::: "memory"); } \
    else if ((T) + 1 < NT) { asm volatile("s_waitcnt vmcnt(0)" ::: "memory"); } \
    __builtin_amdgcn_sched_barrier(0);                                        \
    /* boundary: publish all waves' staging before next tile's ds_reads */    \
    __builtin_amdgcn_s_barrier();                                             \
  } while (0)

  for (int t = 0; t < NT; t += 2) {
    TILE(t, 0);
    TILE(t + 1, 1);
  }

  // epilogue: transpose through LDS; nontemporal coalesced full-line stores
  {
    float* tile = (float*)ldsB;       // [64][268] fp32
    const int P = 268;
#pragma unroll 1
    for (int quarter = 0; quarter < 4; ++quarter) {
      __builtin_amdgcn_s_barrier();
      if (wm == (quarter >> 1)) {
        const int qi0 = (quarter & 1) * 4;
#pragma unroll
        for (int i = 0; i < 4; ++i)
#pragma unroll
          for (int j = 0; j < 4; ++j) {
            const int rl = i * 16 + (lane >> 4) * 4;
            const int cl = wn * 64 + j * 16 + (lane & 15);
#pragma unroll
            for (int r = 0; r < 4; ++r)
              tile[(rl + r) * P + cl] = (float)acc[qi0 + i][j][r];
          }
      }
      __builtin_amdgcn_s_barrier();
#pragma unroll 1
      for (int rr = 0; rr < 8; ++rr) {
        const int rl = wid * 8 + rr;
        const int grow = bm + quarter * 64 + rl;
        const float4 xs4 = Xst[grow];
        const float r1 = xs4.x, r2 = xs4.x * xs4.y, r3 = xs4.x * xs4.z;
        const int n0 = bn + lane * 4;
        const f32x4 v  = *(const f32x4*)&tile[rl * P + lane * 4];
        const f32x4 cs = *(const f32x4*)&colS[n0];
        const f32x4 ca = *(const f32x4*)&colA[n0];
        const f32x4 cb = *(const f32x4*)&colB[n0];
        const f32x4 bi = *(const f32x4*)&bias[n0];
        f32x4 o;
#pragma unroll
        for (int e = 0; e < 4; ++e)
          o[e] = r1 * cs[e] * v[e] - r2 * ca[e] - r3 * cb[e] + bi[e];
        __builtin_nontemporal_store(o, (f32x4*)&C[(size_t)grow * 4096 + n0]);
      }
    }
  }
#undef TILE
#undef MF16
#undef LDA
#undef LDB
#undef STAGE
}

// ---------------------------------------------------------------------------
extern "C" void kernel_launch(void* const* d_in, const int* in_sizes, int n_in,
                              void* d_out, int out_size, void* d_ws, size_t ws_size,
                              hipStream_t stream)
{
  const float* x    = (const float*)d_in[0];  // [4,2048,4096]
  const float* wgt  = (const float*)d_in[1];  // [4096,4096]
  const float* bias = (const float*)d_in[2];  // [4096]
  const float* R    = (const float*)d_in[3];  // [128,128]

  const int K = 4096, N = 4096;
  const int M = in_sizes[0] / K;              // 8192

  uint8_t* Qx = (uint8_t*)d_ws;                          // 32 MB
  uint8_t* Qw = Qx + (size_t)M * K;                      // 16 MB
  float4*  Sx = (float4*)(Qw + (size_t)N * K);           // 128 KB
  float4*  Sw = Sx + M;                                  // 64 KB
  unsigned short* RT3 = (unsigned short*)(Sw + N);       // 96 KB
  float* colS = (float*)((char*)RT3 + 98304);            // 16 KB
  float* colA = colS + N;                                // 16 KB
  float* colB = colA + N;                                // 16 KB

  prep_rt<<<64, 256, 0, stream>>>(R, RT3);
  fq_rot1p<<<M / 16, 512, 0, stream>>>(x,   RT3, Qx, Sx);
  fq_rot1p<<<N / 16, 512, 0, stream>>>(wgt, RT3, Qw, Sw);
  prep_cols<<<N / 256, 256, 0, stream>>>(Sw, colS, colA, colB);

  const int nblk = (M / 256) * (N / 256);     // 512
  gemm256_8ph_i8<<<nblk, 512, 0, stream>>>(Qx, Qw, Sx, colS, colA, colB, bias,
                                           (float*)d_out);
}